// Round 8
// baseline (107.528 us; speedup 1.0000x reference)
//
#include <hip/hip_runtime.h>

constexpr int N_IN    = 128;
constexpr int N_OUT   = 32;
constexpr int LOG_R   = 6;
constexpr int RANGE   = 1 << LOG_R;  // 64 nodes per bucket
constexpr int SCAN_B  = 512;
constexpr int MAXNB   = 2048;        // max buckets (LDS arrays)
constexpr int CHUNK_P = 2048;        // staged pairs per conv2 pass

// ---------------- Kernel 1: h = feat @ W ----------------
__global__ __launch_bounds__(256) void gemm_h(
    const float* __restrict__ feat, const float* __restrict__ W,
    float* __restrict__ h, int n)
{
    __shared__ float Ws[N_IN * N_OUT];  // 16 KB
    for (int i = threadIdx.x; i < (N_IN * N_OUT) / 4; i += 256)
        reinterpret_cast<float4*>(Ws)[i] = reinterpret_cast<const float4*>(W)[i];
    __syncthreads();

    int gid = blockIdx.x * 256 + threadIdx.x;
    int row = gid >> 3;
    if (row >= n) return;
    int cg = (gid & 7) * 4;

    const float4* frow = reinterpret_cast<const float4*>(feat + (size_t)row * N_IN);
    float4 acc = make_float4(0.f, 0.f, 0.f, 0.f);
    #pragma unroll
    for (int k4 = 0; k4 < N_IN / 4; ++k4) {
        float4 f = frow[k4];
        int k = k4 * 4;
        float4 w0 = *reinterpret_cast<const float4*>(&Ws[(k + 0) * N_OUT + cg]);
        float4 w1 = *reinterpret_cast<const float4*>(&Ws[(k + 1) * N_OUT + cg]);
        float4 w2 = *reinterpret_cast<const float4*>(&Ws[(k + 2) * N_OUT + cg]);
        float4 w3 = *reinterpret_cast<const float4*>(&Ws[(k + 3) * N_OUT + cg]);
        acc.x += f.x * w0.x + f.y * w1.x + f.z * w2.x + f.w * w3.x;
        acc.y += f.x * w0.y + f.y * w1.y + f.z * w2.y + f.w * w3.y;
        acc.z += f.x * w0.z + f.y * w1.z + f.z * w2.z + f.w * w3.z;
        acc.w += f.x * w0.w + f.y * w1.w + f.z * w2.w + f.w * w3.w;
    }
    *reinterpret_cast<float4*>(h + (size_t)row * N_OUT + cg) = acc;
}

// ---------------- count: per-chunk bucket histogram (LDS atomics only) ----
__global__ __launch_bounds__(256) void count_k(
    const int* __restrict__ dst, int* __restrict__ cnt, int E, int NB,
    int epc, int ncc)
{
    __shared__ int hist[MAXNB];
    int c = blockIdx.x;
    for (int i = threadIdx.x; i < NB; i += 256) hist[i] = 0;
    __syncthreads();
    int e0 = c * epc, e1 = min(e0 + epc, E);
    for (int e = e0 + (int)threadIdx.x; e < e1; e += 256)
        atomicAdd(&hist[dst[e] >> LOG_R], 1);
    __syncthreads();
    for (int b = threadIdx.x; b < NB; b += 256)
        cnt[b * ncc + c] = hist[b];   // bucket-major matrix
}

// ---------------- hierarchical exclusive scan over m elements -------------
__global__ __launch_bounds__(SCAN_B) void scan1(
    const int* __restrict__ cnt, int* __restrict__ bsum, int m)
{
    __shared__ int s[SCAN_B];
    int g = blockIdx.x * SCAN_B + threadIdx.x;
    s[threadIdx.x] = (g < m) ? cnt[g] : 0;
    __syncthreads();
    for (int off = SCAN_B / 2; off > 0; off >>= 1) {
        if ((int)threadIdx.x < off) s[threadIdx.x] += s[threadIdx.x + off];
        __syncthreads();
    }
    if (threadIdx.x == 0) bsum[blockIdx.x] = s[0];
}

// exclusive scan of nb block sums; single block, loops tiles (nb any size)
__global__ __launch_bounds__(SCAN_B) void scan2(int* __restrict__ bsum, int nb)
{
    __shared__ int s[SCAN_B];
    __shared__ int carry;
    int t = threadIdx.x;
    if (t == 0) carry = 0;
    __syncthreads();
    for (int base = 0; base < nb; base += SCAN_B) {
        int g = base + t;
        int v = (g < nb) ? bsum[g] : 0;
        s[t] = v;
        __syncthreads();
        for (int off = 1; off < SCAN_B; off <<= 1) {
            int x = (t >= off) ? s[t - off] : 0;
            __syncthreads();
            s[t] += x;
            __syncthreads();
        }
        if (g < nb) bsum[g] = s[t] - v + carry;
        __syncthreads();
        if (t == 0) carry += s[SCAN_B - 1];
        __syncthreads();
    }
}

// in-place: base[g] = exclusive_scan(cnt)[g] + bsum[block]
__global__ __launch_bounds__(SCAN_B) void scan3(
    int* __restrict__ base, const int* __restrict__ bsum, int m)
{
    __shared__ int s[SCAN_B];
    int t = threadIdx.x;
    int g = blockIdx.x * SCAN_B + t;
    int v = (g < m) ? base[g] : 0;
    s[t] = v;
    __syncthreads();
    for (int off = 1; off < SCAN_B; off <<= 1) {
        int x = (t >= off) ? s[t - off] : 0;
        __syncthreads();
        s[t] += x;
        __syncthreads();
    }
    if (g < m) base[g] = s[t] - v + bsum[blockIdx.x];
}

// ---------------- partition: bin (src|loc, w) pairs by bucket --------------
__global__ __launch_bounds__(256) void partition_k(
    const int* __restrict__ src, const int* __restrict__ dst,
    const float* __restrict__ w, const int* __restrict__ base,
    int2* __restrict__ sw, int E, int NB, int epc, int ncc)
{
    __shared__ int cur[MAXNB];
    int c = blockIdx.x;
    for (int b = threadIdx.x; b < NB; b += 256)
        cur[b] = base[b * ncc + c];
    __syncthreads();
    int e0 = c * epc, e1 = min(e0 + epc, E);
    for (int e = e0 + (int)threadIdx.x; e < e1; e += 256) {
        int d = dst[e];
        int b = d >> LOG_R;
        int loc = d & (RANGE - 1);
        int pos = atomicAdd(&cur[b], 1);
        sw[pos] = make_int2(src[e] | (loc << 17), __float_as_int(w[e]));
    }
}

// ---------------- conv2: in-LDS node sort + register-accumulate gather -----
__global__ __launch_bounds__(256) void conv2_k(
    const float* __restrict__ h, const int2* __restrict__ sw,
    const int* __restrict__ base, float* __restrict__ out,
    int n, int E, int NB, int ncc)
{
    __shared__ int2 pairs[CHUNK_P];            // 16 KB
    __shared__ unsigned short order[CHUNK_P];  // 4 KB
    __shared__ int cnt[RANGE];
    __shared__ int sc[RANGE];
    __shared__ int start[RANGE + 1];
    __shared__ int cur[RANGE];

    const int b   = blockIdx.x;
    const int tid = threadIdx.x;
    const int g   = tid >> 3;          // 0..31
    const int cg  = (tid & 7) * 4;

    const int seg0 = base[b * ncc];
    const int seg1 = (b + 1 < NB) ? base[(b + 1) * ncc] : E;

    float4 accA = make_float4(0.f, 0.f, 0.f, 0.f);  // node 2g
    float4 accB = make_float4(0.f, 0.f, 0.f, 0.f);  // node 2g+1

    for (int cbase = seg0; cbase < seg1; cbase += CHUNK_P) {
        const int m = min(CHUNK_P, seg1 - cbase);

        if (tid < RANGE) cnt[tid] = 0;
        __syncthreads();

        for (int i = tid; i < m; i += 256) {
            int2 p = sw[cbase + i];
            pairs[i] = p;
            atomicAdd(&cnt[p.x >> 17], 1);
        }
        __syncthreads();

        int v = 0;
        if (tid < RANGE) { v = cnt[tid]; sc[tid] = v; }
        __syncthreads();
        #pragma unroll
        for (int off = 1; off < RANGE; off <<= 1) {
            int x = (tid < RANGE && tid >= off) ? sc[tid - off] : 0;
            __syncthreads();
            if (tid < RANGE) sc[tid] += x;
            __syncthreads();
        }
        if (tid < RANGE) { start[tid] = sc[tid] - v; cur[tid] = sc[tid] - v; }
        if (tid == RANGE - 1) start[RANGE] = sc[RANGE - 1];
        __syncthreads();

        for (int i = tid; i < m; i += 256) {
            int loc = pairs[i].x >> 17;
            int pos = atomicAdd(&cur[loc], 1);
            order[pos] = (unsigned short)i;
        }
        __syncthreads();

        int k  = start[2 * g];
        int ke = start[2 * g + 2];
        for (; k + 3 < ke; k += 4) {
            int i0 = order[k + 0], i1 = order[k + 1];
            int i2 = order[k + 2], i3 = order[k + 3];
            int2 p0 = pairs[i0], p1 = pairs[i1], p2 = pairs[i2], p3 = pairs[i3];
            float4 h0 = *reinterpret_cast<const float4*>(h + (size_t)(p0.x & 0x1FFFF) * N_OUT + cg);
            float4 h1 = *reinterpret_cast<const float4*>(h + (size_t)(p1.x & 0x1FFFF) * N_OUT + cg);
            float4 h2 = *reinterpret_cast<const float4*>(h + (size_t)(p2.x & 0x1FFFF) * N_OUT + cg);
            float4 h3 = *reinterpret_cast<const float4*>(h + (size_t)(p3.x & 0x1FFFF) * N_OUT + cg);
            #define ACC_STEP(p, hv)                                            \
            {                                                                  \
                float wv  = __int_as_float(p.y);                               \
                int   odd = (p.x >> 17) & 1;                                   \
                float wa = odd ? 0.f : wv, wb = odd ? wv : 0.f;                \
                accA.x += hv.x * wa; accA.y += hv.y * wa;                      \
                accA.z += hv.z * wa; accA.w += hv.w * wa;                      \
                accB.x += hv.x * wb; accB.y += hv.y * wb;                      \
                accB.z += hv.z * wb; accB.w += hv.w * wb;                      \
            }
            ACC_STEP(p0, h0) ACC_STEP(p1, h1) ACC_STEP(p2, h2) ACC_STEP(p3, h3)
        }
        for (; k < ke; ++k) {
            int i = order[k];
            int2 p = pairs[i];
            float4 hv = *reinterpret_cast<const float4*>(h + (size_t)(p.x & 0x1FFFF) * N_OUT + cg);
            ACC_STEP(p, hv)
            #undef ACC_STEP
        }
        __syncthreads();
    }

    const int lo = b * RANGE;
    int node0 = lo + 2 * g;
    if (node0 < n)
        *reinterpret_cast<float4*>(out + (size_t)node0 * N_OUT + cg) = accA;
    if (node0 + 1 < n)
        *reinterpret_cast<float4*>(out + (size_t)(node0 + 1) * N_OUT + cg) = accB;
}

// ---------------- Fallback: fused (no workspace) ----------------
__global__ __launch_bounds__(256) void fused_edge(
    const float* __restrict__ feat, const float* __restrict__ W,
    const float* __restrict__ edge_w, const int* __restrict__ src,
    const int* __restrict__ dst, float* __restrict__ out, int E)
{
    __shared__ float Ws[N_IN * N_OUT];
    for (int i = threadIdx.x; i < (N_IN * N_OUT) / 4; i += 256)
        reinterpret_cast<float4*>(Ws)[i] = reinterpret_cast<const float4*>(W)[i];
    __syncthreads();
    int gid = blockIdx.x * 256 + threadIdx.x;
    int e = gid >> 3;
    if (e >= E) return;
    int cg = (gid & 7) * 4;
    int s = src[e];
    int d = dst[e];
    float w = edge_w[e];
    const float4* frow = reinterpret_cast<const float4*>(feat + (size_t)s * N_IN);
    float4 acc = make_float4(0.f, 0.f, 0.f, 0.f);
    #pragma unroll
    for (int k4 = 0; k4 < N_IN / 4; ++k4) {
        float4 f = frow[k4];
        int k = k4 * 4;
        float4 w0 = *reinterpret_cast<const float4*>(&Ws[(k + 0) * N_OUT + cg]);
        float4 w1 = *reinterpret_cast<const float4*>(&Ws[(k + 1) * N_OUT + cg]);
        float4 w2 = *reinterpret_cast<const float4*>(&Ws[(k + 2) * N_OUT + cg]);
        float4 w3 = *reinterpret_cast<const float4*>(&Ws[(k + 3) * N_OUT + cg]);
        acc.x += f.x * w0.x + f.y * w1.x + f.z * w2.x + f.w * w3.x;
        acc.y += f.x * w0.y + f.y * w1.y + f.z * w2.y + f.w * w3.y;
        acc.z += f.x * w0.z + f.y * w1.z + f.z * w2.z + f.w * w3.z;
        acc.w += f.x * w0.w + f.y * w1.w + f.z * w2.w + f.w * w3.w;
    }
    float* o = out + (size_t)d * N_OUT + cg;
    atomicAdd(o + 0, acc.x * w);
    atomicAdd(o + 1, acc.y * w);
    atomicAdd(o + 2, acc.z * w);
    atomicAdd(o + 3, acc.w * w);
}

extern "C" void kernel_launch(void* const* d_in, const int* in_sizes, int n_in,
                              void* d_out, int out_size, void* d_ws, size_t ws_size,
                              hipStream_t stream) {
    const float* feat   = (const float*)d_in[0];
    const float* W      = (const float*)d_in[1];
    const float* edge_w = (const float*)d_in[2];
    const int*   src    = (const int*)d_in[3];
    const int*   dst    = (const int*)d_in[4];
    float* out = (float*)d_out;

    int n = in_sizes[0] / N_IN;   // 100000
    int E = in_sizes[2];          // 1600000

    int NB = (n + RANGE - 1) / RANGE;        // 1563

    // pick the largest chunk count whose workspace fits
    int ncc = 0;
    size_t off_h = 0, off_base = 0, off_bsum = 0, off_sw = 0;
    int m = 0, nsb = 0, epc = 0;
    for (int try_ncc : {512, 256, 128}) {
        m   = NB * try_ncc;
        nsb = (m + SCAN_B - 1) / SCAN_B;
        off_h    = 0;
        off_base = off_h + (size_t)n * N_OUT * sizeof(float);
        off_bsum = off_base + (size_t)m * sizeof(int);
        off_sw   = (off_bsum + (size_t)nsb * sizeof(int) + 15) & ~(size_t)15;
        size_t need = off_sw + (size_t)E * sizeof(int2);
        if (ws_size >= need) { ncc = try_ncc; break; }
    }

    bool ok = (ncc > 0) && (n <= (1 << 17)) && (NB <= MAXNB);

    if (ok) {
        epc = (E + ncc - 1) / ncc;

        char* ws = (char*)d_ws;
        float* h    = (float*)(ws + off_h);
        int*   base = (int*)(ws + off_base);   // cnt matrix, scanned in place
        int*   bsum = (int*)(ws + off_bsum);
        int2*  sw   = (int2*)(ws + off_sw);

        long gthreads = (long)n * 8;
        gemm_h<<<(int)((gthreads + 255) / 256), 256, 0, stream>>>(feat, W, h, n);

        count_k<<<ncc, 256, 0, stream>>>(dst, base, E, NB, epc, ncc);
        scan1<<<nsb, SCAN_B, 0, stream>>>(base, bsum, m);
        scan2<<<1, SCAN_B, 0, stream>>>(bsum, nsb);
        scan3<<<nsb, SCAN_B, 0, stream>>>(base, bsum, m);
        partition_k<<<ncc, 256, 0, stream>>>(src, dst, edge_w, base, sw, E, NB, epc, ncc);
        conv2_k<<<NB, 256, 0, stream>>>(h, sw, base, out, n, E, NB, ncc);
    } else {
        hipMemsetAsync(d_out, 0, (size_t)out_size * sizeof(float), stream);
        long sthreads = (long)E * 8;
        fused_edge<<<(int)((sthreads + 255) / 256), 256, 0, stream>>>(feat, W, edge_w, src, dst, out, E);
    }
}

// Round 9
// 94.187 us; speedup vs baseline: 1.1416x; 1.1416x over previous
//
#include <hip/hip_runtime.h>

constexpr int N_IN    = 128;
constexpr int N_OUT   = 32;
constexpr int LOG_R   = 6;
constexpr int RANGE   = 1 << LOG_R;  // 64 nodes per bucket
constexpr int MAXNB   = 2048;        // max buckets (LDS hist)
constexpr int NCC     = 256;         // edge chunks (fits 256-wide LDS scan)
constexpr int CHUNK_P = 2048;        // staged pairs per conv3 pass

// ---------------- Kernel 1: h = feat @ W ----------------
__global__ __launch_bounds__(256) void gemm_h(
    const float* __restrict__ feat, const float* __restrict__ W,
    float* __restrict__ h, int n)
{
    __shared__ float Ws[N_IN * N_OUT];  // 16 KB
    for (int i = threadIdx.x; i < (N_IN * N_OUT) / 4; i += 256)
        reinterpret_cast<float4*>(Ws)[i] = reinterpret_cast<const float4*>(W)[i];
    __syncthreads();

    int gid = blockIdx.x * 256 + threadIdx.x;
    int row = gid >> 3;
    if (row >= n) return;
    int cg = (gid & 7) * 4;

    const float4* frow = reinterpret_cast<const float4*>(feat + (size_t)row * N_IN);
    float4 acc = make_float4(0.f, 0.f, 0.f, 0.f);
    #pragma unroll
    for (int k4 = 0; k4 < N_IN / 4; ++k4) {
        float4 f = frow[k4];
        int k = k4 * 4;
        float4 w0 = *reinterpret_cast<const float4*>(&Ws[(k + 0) * N_OUT + cg]);
        float4 w1 = *reinterpret_cast<const float4*>(&Ws[(k + 1) * N_OUT + cg]);
        float4 w2 = *reinterpret_cast<const float4*>(&Ws[(k + 2) * N_OUT + cg]);
        float4 w3 = *reinterpret_cast<const float4*>(&Ws[(k + 3) * N_OUT + cg]);
        acc.x += f.x * w0.x + f.y * w1.x + f.z * w2.x + f.w * w3.x;
        acc.y += f.x * w0.y + f.y * w1.y + f.z * w2.y + f.w * w3.y;
        acc.z += f.x * w0.z + f.y * w1.z + f.z * w2.z + f.w * w3.z;
        acc.w += f.x * w0.w + f.y * w1.w + f.z * w2.w + f.w * w3.w;
    }
    *reinterpret_cast<float4*>(h + (size_t)row * N_OUT + cg) = acc;
}

// ---------------- partition2: chunk-local sort, chunk-contiguous output ----
// Block c owns edges [c*epc, c*epc+epc). LDS histogram over all NB buckets,
// in-LDS hierarchical scan, per-chunk offset table (coalesced write), then
// pair scatter confined to the chunk's own epc*8B (~50 KB) region -> L2
// absorbs and writes back clean full lines. Zero global atomics, no global
// scan pipeline needed (chunk base = c*epc by construction).
__global__ __launch_bounds__(256) void partition2_k(
    const int* __restrict__ src, const int* __restrict__ dst,
    const float* __restrict__ w, int* __restrict__ tbl,
    int2* __restrict__ sw, int E, int NB, int epc)
{
    __shared__ int hist[MAXNB];
    __shared__ int wscan[256];

    const int c   = blockIdx.x;
    const int tid = threadIdx.x;
    const int e0  = c * epc;
    const int e1  = min(e0 + epc, E);
    const int m   = max(e1 - e0, 0);
    const int slots = (NB + 255) / 256;

    for (int i = tid; i < NB; i += 256) hist[i] = 0;
    __syncthreads();

    // pass 1: histogram
    for (int e = e0 + tid; e < e1; e += 256)
        atomicAdd(&hist[dst[e] >> LOG_R], 1);
    __syncthreads();

    // hierarchical exclusive scan over NB counters:
    // thread-local serial sum -> 256-wide scan -> serial write-back
    int tsum = 0;
    int base = tid * slots;
    for (int j = 0; j < slots; ++j) {
        int idx = base + j;
        if (idx < NB) tsum += hist[idx];
    }
    wscan[tid] = tsum;
    __syncthreads();
    for (int off = 1; off < 256; off <<= 1) {
        int x = (tid >= off) ? wscan[tid - off] : 0;
        __syncthreads();
        wscan[tid] += x;
        __syncthreads();
    }
    int run = wscan[tid] - tsum;   // exclusive offset for this thread's slots
    __syncthreads();
    for (int j = 0; j < slots; ++j) {
        int idx = base + j;
        if (idx < NB) {
            int cval = hist[idx];
            tbl[(size_t)c * (NB + 1) + idx] = run;  // local start within chunk
            hist[idx] = run;                        // becomes cursor
            run += cval;
        }
    }
    if (tid == 0) tbl[(size_t)c * (NB + 1) + NB] = m;
    __syncthreads();

    // pass 2: scatter pairs into the chunk's contiguous region
    int2* out = sw + (size_t)c * epc;
    for (int e = e0 + tid; e < e1; e += 256) {
        int d   = dst[e];
        int b   = d >> LOG_R;
        int loc = d & (RANGE - 1);
        int pos = atomicAdd(&hist[b], 1);
        out[pos] = make_int2(src[e] | (loc << 17), __float_as_int(w[e]));
    }
}

// ---------------- conv3: run-gather + in-LDS node sort + reg accumulate ----
// Block = bucket b (64 nodes). Collect this bucket's runs from all chunks
// (binary search over per-chunk prefix), stage CHUNK_P pairs in LDS, node-
// sort them (hist+scan+index scatter), then 32 groups of 8 threads register-
// accumulate 2 nodes each. One guarded float4 store per node at the end.
__global__ __launch_bounds__(256) void conv3_k(
    const float* __restrict__ h, const int2* __restrict__ sw,
    const int* __restrict__ tbl, float* __restrict__ out,
    int n, int NB, int ncc, int epc)
{
    __shared__ int2 pairs[CHUNK_P];            // 16 KB
    __shared__ unsigned short order[CHUNK_P];  // 4 KB
    __shared__ int cnt[RANGE];
    __shared__ int sc[RANGE];
    __shared__ int start[RANGE + 1];
    __shared__ int cur[RANGE];
    __shared__ int rs[256];
    __shared__ int ps[257];
    __shared__ int stmp[256];

    const int b   = blockIdx.x;
    const int tid = threadIdx.x;
    const int g   = tid >> 3;          // 0..31
    const int cg  = (tid & 7) * 4;

    // per-chunk run starts/lengths for this bucket; prefix over chunks
    int len = 0;
    if (tid < ncc) {
        int s0 = tbl[(size_t)tid * (NB + 1) + b];
        int s1 = tbl[(size_t)tid * (NB + 1) + b + 1];
        rs[tid] = s0;
        len = s1 - s0;
    }
    stmp[tid] = len;
    __syncthreads();
    for (int off = 1; off < 256; off <<= 1) {
        int x = (tid >= off) ? stmp[tid - off] : 0;
        __syncthreads();
        stmp[tid] += x;
        __syncthreads();
    }
    ps[tid + 1] = stmp[tid];
    if (tid == 0) ps[0] = 0;
    __syncthreads();
    const int deg = ps[ncc];

    float4 accA = make_float4(0.f, 0.f, 0.f, 0.f);  // node 2g
    float4 accB = make_float4(0.f, 0.f, 0.f, 0.f);  // node 2g+1

    for (int cbase = 0; cbase < deg; cbase += CHUNK_P) {
        const int m = min(CHUNK_P, deg - cbase);

        // stage: virtual index -> (chunk, offset) via binary search on ps
        for (int i = tid; i < m; i += 256) {
            int gidx = cbase + i;
            int lo = 0, hi = ncc - 1;
            while (lo < hi) {
                int mid = (lo + hi + 1) >> 1;
                if (ps[mid] <= gidx) lo = mid; else hi = mid - 1;
            }
            int off = gidx - ps[lo];
            pairs[i] = sw[(size_t)lo * epc + rs[lo] + off];
        }
        if (tid < RANGE) cnt[tid] = 0;
        __syncthreads();

        for (int i = tid; i < m; i += 256)
            atomicAdd(&cnt[pairs[i].x >> 17], 1);
        __syncthreads();

        int v = 0;
        if (tid < RANGE) { v = cnt[tid]; sc[tid] = v; }
        __syncthreads();
        #pragma unroll
        for (int off = 1; off < RANGE; off <<= 1) {
            int x = (tid < RANGE && tid >= off) ? sc[tid - off] : 0;
            __syncthreads();
            if (tid < RANGE) sc[tid] += x;
            __syncthreads();
        }
        if (tid < RANGE) { start[tid] = sc[tid] - v; cur[tid] = sc[tid] - v; }
        if (tid == RANGE - 1) start[RANGE] = sc[RANGE - 1];
        __syncthreads();

        for (int i = tid; i < m; i += 256) {
            int loc = pairs[i].x >> 17;
            int pos = atomicAdd(&cur[loc], 1);
            order[pos] = (unsigned short)i;
        }
        __syncthreads();

        int k  = start[2 * g];
        int ke = start[2 * g + 2];
        for (; k + 3 < ke; k += 4) {
            int i0 = order[k + 0], i1 = order[k + 1];
            int i2 = order[k + 2], i3 = order[k + 3];
            int2 p0 = pairs[i0], p1 = pairs[i1], p2 = pairs[i2], p3 = pairs[i3];
            float4 h0 = *reinterpret_cast<const float4*>(h + (size_t)(p0.x & 0x1FFFF) * N_OUT + cg);
            float4 h1 = *reinterpret_cast<const float4*>(h + (size_t)(p1.x & 0x1FFFF) * N_OUT + cg);
            float4 h2 = *reinterpret_cast<const float4*>(h + (size_t)(p2.x & 0x1FFFF) * N_OUT + cg);
            float4 h3 = *reinterpret_cast<const float4*>(h + (size_t)(p3.x & 0x1FFFF) * N_OUT + cg);
            #define ACC_STEP(p, hv)                                            \
            {                                                                  \
                float wv  = __int_as_float(p.y);                               \
                int   odd = (p.x >> 17) & 1;                                   \
                float wa = odd ? 0.f : wv, wb = odd ? wv : 0.f;                \
                accA.x += hv.x * wa; accA.y += hv.y * wa;                      \
                accA.z += hv.z * wa; accA.w += hv.w * wa;                      \
                accB.x += hv.x * wb; accB.y += hv.y * wb;                      \
                accB.z += hv.z * wb; accB.w += hv.w * wb;                      \
            }
            ACC_STEP(p0, h0) ACC_STEP(p1, h1) ACC_STEP(p2, h2) ACC_STEP(p3, h3)
        }
        for (; k < ke; ++k) {
            int i = order[k];
            int2 p = pairs[i];
            float4 hv = *reinterpret_cast<const float4*>(h + (size_t)(p.x & 0x1FFFF) * N_OUT + cg);
            ACC_STEP(p, hv)
            #undef ACC_STEP
        }
        __syncthreads();
    }

    const int lo2 = b * RANGE;
    int node0 = lo2 + 2 * g;
    if (node0 < n)
        *reinterpret_cast<float4*>(out + (size_t)node0 * N_OUT + cg) = accA;
    if (node0 + 1 < n)
        *reinterpret_cast<float4*>(out + (size_t)(node0 + 1) * N_OUT + cg) = accB;
}

// ---------------- Fallback: fused (no workspace) ----------------
__global__ __launch_bounds__(256) void fused_edge(
    const float* __restrict__ feat, const float* __restrict__ W,
    const float* __restrict__ edge_w, const int* __restrict__ src,
    const int* __restrict__ dst, float* __restrict__ out, int E)
{
    __shared__ float Ws[N_IN * N_OUT];
    for (int i = threadIdx.x; i < (N_IN * N_OUT) / 4; i += 256)
        reinterpret_cast<float4*>(Ws)[i] = reinterpret_cast<const float4*>(W)[i];
    __syncthreads();
    int gid = blockIdx.x * 256 + threadIdx.x;
    int e = gid >> 3;
    if (e >= E) return;
    int cg = (gid & 7) * 4;
    int s = src[e];
    int d = dst[e];
    float w = edge_w[e];
    const float4* frow = reinterpret_cast<const float4*>(feat + (size_t)s * N_IN);
    float4 acc = make_float4(0.f, 0.f, 0.f, 0.f);
    #pragma unroll
    for (int k4 = 0; k4 < N_IN / 4; ++k4) {
        float4 f = frow[k4];
        int k = k4 * 4;
        float4 w0 = *reinterpret_cast<const float4*>(&Ws[(k + 0) * N_OUT + cg]);
        float4 w1 = *reinterpret_cast<const float4*>(&Ws[(k + 1) * N_OUT + cg]);
        float4 w2 = *reinterpret_cast<const float4*>(&Ws[(k + 2) * N_OUT + cg]);
        float4 w3 = *reinterpret_cast<const float4*>(&Ws[(k + 3) * N_OUT + cg]);
        acc.x += f.x * w0.x + f.y * w1.x + f.z * w2.x + f.w * w3.x;
        acc.y += f.x * w0.y + f.y * w1.y + f.z * w2.y + f.w * w3.y;
        acc.z += f.x * w0.z + f.y * w1.z + f.z * w2.z + f.w * w3.z;
        acc.w += f.x * w0.w + f.y * w1.w + f.z * w2.w + f.w * w3.w;
    }
    float* o = out + (size_t)d * N_OUT + cg;
    atomicAdd(o + 0, acc.x * w);
    atomicAdd(o + 1, acc.y * w);
    atomicAdd(o + 2, acc.z * w);
    atomicAdd(o + 3, acc.w * w);
}

extern "C" void kernel_launch(void* const* d_in, const int* in_sizes, int n_in,
                              void* d_out, int out_size, void* d_ws, size_t ws_size,
                              hipStream_t stream) {
    const float* feat   = (const float*)d_in[0];
    const float* W      = (const float*)d_in[1];
    const float* edge_w = (const float*)d_in[2];
    const int*   src    = (const int*)d_in[3];
    const int*   dst    = (const int*)d_in[4];
    float* out = (float*)d_out;

    int n = in_sizes[0] / N_IN;   // 100000
    int E = in_sizes[2];          // 1600000

    int NB  = (n + RANGE - 1) / RANGE;   // 1563
    int ncc = NCC;                       // 256
    int epc = (E + ncc - 1) / ncc;       // 6250

    size_t off_h   = 0;
    size_t off_tbl = off_h + (size_t)n * N_OUT * sizeof(float);
    size_t off_sw  = (off_tbl + (size_t)ncc * (NB + 1) * sizeof(int) + 15) & ~(size_t)15;
    size_t need    = off_sw + (size_t)ncc * epc * sizeof(int2);

    bool ok = (ws_size >= need) && (n <= (1 << 17)) && (NB <= MAXNB);

    if (ok) {
        char* ws = (char*)d_ws;
        float* h   = (float*)(ws + off_h);
        int*   tbl = (int*)(ws + off_tbl);
        int2*  sw  = (int2*)(ws + off_sw);

        long gthreads = (long)n * 8;
        gemm_h<<<(int)((gthreads + 255) / 256), 256, 0, stream>>>(feat, W, h, n);
        partition2_k<<<ncc, 256, 0, stream>>>(src, dst, edge_w, tbl, sw, E, NB, epc);
        conv3_k<<<NB, 256, 0, stream>>>(h, sw, tbl, out, n, NB, ncc, epc);
    } else {
        hipMemsetAsync(d_out, 0, (size_t)out_size * sizeof(float), stream);
        long sthreads = (long)E * 8;
        fused_edge<<<(int)((sthreads + 255) / 256), 256, 0, stream>>>(feat, W, edge_w, src, dst, out, E);
    }
}

// Round 11
// 80.330 us; speedup vs baseline: 1.3386x; 1.1725x over previous
//
#include <hip/hip_runtime.h>
#include <hip/hip_fp16.h>

constexpr int N_IN    = 128;
constexpr int N_OUT   = 32;
constexpr int LOG_R   = 6;
constexpr int RANGE   = 1 << LOG_R;  // 64 nodes per bucket
constexpr int MAXNB   = 2048;        // max buckets (LDS hist)
constexpr int NCC     = 256;         // edge chunks (fits 256-wide LDS scans in conv3)
constexpr int PBLK    = 512;         // partition2 threads (8 waves: latency cover)
constexpr int CHUNK_P = 2048;        // staged pairs per conv3 pass

union H4 { uint2 u; __half2 h2[2]; };

// ---------------- Kernel 1: h = feat @ W  (h stored as f16) ----------------
__global__ __launch_bounds__(256) void gemm_h(
    const float* __restrict__ feat, const float* __restrict__ W,
    __half* __restrict__ h, int n)
{
    __shared__ float Ws[N_IN * N_OUT];  // 16 KB
    for (int i = threadIdx.x; i < (N_IN * N_OUT) / 4; i += 256)
        reinterpret_cast<float4*>(Ws)[i] = reinterpret_cast<const float4*>(W)[i];
    __syncthreads();

    int gid = blockIdx.x * 256 + threadIdx.x;
    int row = gid >> 3;
    if (row >= n) return;
    int cg = (gid & 7) * 4;

    const float4* frow = reinterpret_cast<const float4*>(feat + (size_t)row * N_IN);
    float4 acc = make_float4(0.f, 0.f, 0.f, 0.f);
    #pragma unroll
    for (int k4 = 0; k4 < N_IN / 4; ++k4) {
        float4 f = frow[k4];
        int k = k4 * 4;
        float4 w0 = *reinterpret_cast<const float4*>(&Ws[(k + 0) * N_OUT + cg]);
        float4 w1 = *reinterpret_cast<const float4*>(&Ws[(k + 1) * N_OUT + cg]);
        float4 w2 = *reinterpret_cast<const float4*>(&Ws[(k + 2) * N_OUT + cg]);
        float4 w3 = *reinterpret_cast<const float4*>(&Ws[(k + 3) * N_OUT + cg]);
        acc.x += f.x * w0.x + f.y * w1.x + f.z * w2.x + f.w * w3.x;
        acc.y += f.x * w0.y + f.y * w1.y + f.z * w2.y + f.w * w3.y;
        acc.z += f.x * w0.z + f.y * w1.z + f.z * w2.z + f.w * w3.z;
        acc.w += f.x * w0.w + f.y * w1.w + f.z * w2.w + f.w * w3.w;
    }
    H4 v;
    v.h2[0] = __float22half2_rn(make_float2(acc.x, acc.y));
    v.h2[1] = __float22half2_rn(make_float2(acc.z, acc.w));
    *reinterpret_cast<uint2*>(h + (size_t)row * N_OUT + cg) = v.u;
}

// ---------------- partition2: chunk-local sort, chunk-contiguous output ----
// 512 threads (8 waves) for latency cover. Block c owns edges
// [c*epc, c*epc+epc). LDS histogram over all NB buckets, in-LDS scan,
// per-chunk offset table, then pair scatter confined to the chunk's own
// ~50 KB region (L2-absorbed, clean writeback). Zero global atomics.
__global__ __launch_bounds__(PBLK) void partition2_k(
    const int* __restrict__ src, const int* __restrict__ dst,
    const float* __restrict__ w, int* __restrict__ tbl,
    int2* __restrict__ sw, int E, int NB, int epc)
{
    __shared__ int hist[MAXNB];
    __shared__ int wscan[PBLK];

    const int c   = blockIdx.x;
    const int tid = threadIdx.x;
    const int e0  = c * epc;
    const int e1  = min(e0 + epc, E);
    const int m   = max(e1 - e0, 0);
    const int slots = (NB + PBLK - 1) / PBLK;

    for (int i = tid; i < NB; i += PBLK) hist[i] = 0;
    __syncthreads();

    // pass 1: histogram
    for (int e = e0 + tid; e < e1; e += PBLK)
        atomicAdd(&hist[dst[e] >> LOG_R], 1);
    __syncthreads();

    // exclusive scan over NB counters: thread-serial sum -> wide scan -> write-back
    int tsum = 0;
    int base = tid * slots;
    for (int j = 0; j < slots; ++j) {
        int idx = base + j;
        if (idx < NB) tsum += hist[idx];
    }
    wscan[tid] = tsum;
    __syncthreads();
    for (int off = 1; off < PBLK; off <<= 1) {
        int x = (tid >= off) ? wscan[tid - off] : 0;
        __syncthreads();
        wscan[tid] += x;
        __syncthreads();
    }
    int run = wscan[tid] - tsum;
    __syncthreads();
    for (int j = 0; j < slots; ++j) {
        int idx = base + j;
        if (idx < NB) {
            int cval = hist[idx];
            tbl[(size_t)c * (NB + 1) + idx] = run;  // local start within chunk
            hist[idx] = run;                        // becomes cursor
            run += cval;
        }
    }
    if (tid == 0) tbl[(size_t)c * (NB + 1) + NB] = m;
    __syncthreads();

    // pass 2: scatter pairs into the chunk's contiguous region
    int2* outp = sw + (size_t)c * epc;
    for (int e = e0 + tid; e < e1; e += PBLK) {
        int d   = dst[e];
        int b   = d >> LOG_R;
        int loc = d & (RANGE - 1);
        int pos = atomicAdd(&hist[b], 1);
        outp[pos] = make_int2(src[e] | (loc << 17), __float_as_int(w[e]));
    }
}

// ---------------- conv3: run-gather + in-LDS node sort + reg accumulate ----
__global__ __launch_bounds__(256) void conv3_k(
    const __half* __restrict__ h, const int2* __restrict__ sw,
    const int* __restrict__ tbl, float* __restrict__ out,
    int n, int NB, int ncc, int epc)
{
    __shared__ int2 pairs[CHUNK_P];            // 16 KB
    __shared__ unsigned short order[CHUNK_P];  // 4 KB
    __shared__ int cnt[RANGE];
    __shared__ int sc[RANGE];
    __shared__ int start[RANGE + 1];
    __shared__ int cur[RANGE];
    __shared__ int rs[NCC];
    __shared__ int ps[NCC + 1];
    __shared__ int stmp[256];

    const int b   = blockIdx.x;
    const int tid = threadIdx.x;
    const int g   = tid >> 3;          // 0..31
    const int cg  = (tid & 7) * 4;

    // per-chunk run starts/lengths for this bucket; prefix over chunks
    int len = 0;
    if (tid < ncc) {
        int s0 = tbl[(size_t)tid * (NB + 1) + b];
        int s1 = tbl[(size_t)tid * (NB + 1) + b + 1];
        rs[tid] = s0;
        len = s1 - s0;
    }
    stmp[tid] = len;
    __syncthreads();
    for (int off = 1; off < 256; off <<= 1) {
        int x = (tid >= off) ? stmp[tid - off] : 0;
        __syncthreads();
        stmp[tid] += x;
        __syncthreads();
    }
    ps[tid + 1] = stmp[tid];
    if (tid == 0) ps[0] = 0;
    __syncthreads();
    const int deg = ps[ncc];

    float4 accA = make_float4(0.f, 0.f, 0.f, 0.f);  // node 2g
    float4 accB = make_float4(0.f, 0.f, 0.f, 0.f);  // node 2g+1

    for (int cbase = 0; cbase < deg; cbase += CHUNK_P) {
        const int m = min(CHUNK_P, deg - cbase);

        // stage: virtual index -> (chunk, offset) via binary search on ps
        for (int i = tid; i < m; i += 256) {
            int gidx = cbase + i;
            int lo = 0, hi = ncc - 1;
            while (lo < hi) {
                int mid = (lo + hi + 1) >> 1;
                if (ps[mid] <= gidx) lo = mid; else hi = mid - 1;
            }
            int off = gidx - ps[lo];
            pairs[i] = sw[(size_t)lo * epc + rs[lo] + off];
        }
        if (tid < RANGE) cnt[tid] = 0;
        __syncthreads();

        for (int i = tid; i < m; i += 256)
            atomicAdd(&cnt[pairs[i].x >> 17], 1);
        __syncthreads();

        int v = 0;
        if (tid < RANGE) { v = cnt[tid]; sc[tid] = v; }
        __syncthreads();
        #pragma unroll
        for (int off = 1; off < RANGE; off <<= 1) {
            int x = (tid < RANGE && tid >= off) ? sc[tid - off] : 0;
            __syncthreads();
            if (tid < RANGE) sc[tid] += x;
            __syncthreads();
        }
        if (tid < RANGE) { start[tid] = sc[tid] - v; cur[tid] = sc[tid] - v; }
        if (tid == RANGE - 1) start[RANGE] = sc[RANGE - 1];
        __syncthreads();

        for (int i = tid; i < m; i += 256) {
            int loc = pairs[i].x >> 17;
            int pos = atomicAdd(&cur[loc], 1);
            order[pos] = (unsigned short)i;
        }
        __syncthreads();

        int k  = start[2 * g];
        int ke = start[2 * g + 2];
        // unique names via token pasting (R10 compile-fix)
        #define LOAD_H(p, f01, f23)                                            \
            H4 _u##f01;                                                        \
            _u##f01.u = *reinterpret_cast<const uint2*>(                       \
                h + (size_t)((p).x & 0x1FFFF) * N_OUT + cg);                   \
            float2 f01 = __half22float2(_u##f01.h2[0]);                        \
            float2 f23 = __half22float2(_u##f01.h2[1]);
        #define ACC_STEP(p, f01, f23)                                          \
        {                                                                      \
            float wv  = __int_as_float((p).y);                                 \
            int   odd = ((p).x >> 17) & 1;                                     \
            float wa = odd ? 0.f : wv, wb = odd ? wv : 0.f;                    \
            accA.x += f01.x * wa; accA.y += f01.y * wa;                        \
            accA.z += f23.x * wa; accA.w += f23.y * wa;                        \
            accB.x += f01.x * wb; accB.y += f01.y * wb;                        \
            accB.z += f23.x * wb; accB.w += f23.y * wb;                        \
        }
        for (; k + 3 < ke; k += 4) {
            int i0 = order[k + 0], i1 = order[k + 1];
            int i2 = order[k + 2], i3 = order[k + 3];
            int2 p0 = pairs[i0], p1 = pairs[i1], p2 = pairs[i2], p3 = pairs[i3];
            LOAD_H(p0, a01, a23)
            LOAD_H(p1, b01, b23)
            LOAD_H(p2, c01, c23)
            LOAD_H(p3, d01, d23)
            ACC_STEP(p0, a01, a23)
            ACC_STEP(p1, b01, b23)
            ACC_STEP(p2, c01, c23)
            ACC_STEP(p3, d01, d23)
        }
        for (; k < ke; ++k) {
            int i = order[k];
            int2 p = pairs[i];
            LOAD_H(p, e01, e23)
            ACC_STEP(p, e01, e23)
        }
        #undef LOAD_H
        #undef ACC_STEP
        __syncthreads();
    }

    const int lo2 = b * RANGE;
    int node0 = lo2 + 2 * g;
    if (node0 < n)
        *reinterpret_cast<float4*>(out + (size_t)node0 * N_OUT + cg) = accA;
    if (node0 + 1 < n)
        *reinterpret_cast<float4*>(out + (size_t)(node0 + 1) * N_OUT + cg) = accB;
}

// ---------------- Fallback: fused (no workspace) ----------------
__global__ __launch_bounds__(256) void fused_edge(
    const float* __restrict__ feat, const float* __restrict__ W,
    const float* __restrict__ edge_w, const int* __restrict__ src,
    const int* __restrict__ dst, float* __restrict__ out, int E)
{
    __shared__ float Ws[N_IN * N_OUT];
    for (int i = threadIdx.x; i < (N_IN * N_OUT) / 4; i += 256)
        reinterpret_cast<float4*>(Ws)[i] = reinterpret_cast<const float4*>(W)[i];
    __syncthreads();
    int gid = blockIdx.x * 256 + threadIdx.x;
    int e = gid >> 3;
    if (e >= E) return;
    int cg = (gid & 7) * 4;
    int s = src[e];
    int d = dst[e];
    float w = edge_w[e];
    const float4* frow = reinterpret_cast<const float4*>(feat + (size_t)s * N_IN);
    float4 acc = make_float4(0.f, 0.f, 0.f, 0.f);
    #pragma unroll
    for (int k4 = 0; k4 < N_IN / 4; ++k4) {
        float4 f = frow[k4];
        int k = k4 * 4;
        float4 w0 = *reinterpret_cast<const float4*>(&Ws[(k + 0) * N_OUT + cg]);
        float4 w1 = *reinterpret_cast<const float4*>(&Ws[(k + 1) * N_OUT + cg]);
        float4 w2 = *reinterpret_cast<const float4*>(&Ws[(k + 2) * N_OUT + cg]);
        float4 w3 = *reinterpret_cast<const float4*>(&Ws[(k + 3) * N_OUT + cg]);
        acc.x += f.x * w0.x + f.y * w1.x + f.z * w2.x + f.w * w3.x;
        acc.y += f.x * w0.y + f.y * w1.y + f.z * w2.y + f.w * w3.y;
        acc.z += f.x * w0.z + f.y * w1.z + f.z * w2.z + f.w * w3.z;
        acc.w += f.x * w0.w + f.y * w1.w + f.z * w2.w + f.w * w3.w;
    }
    float* o = out + (size_t)d * N_OUT + cg;
    atomicAdd(o + 0, acc.x * w);
    atomicAdd(o + 1, acc.y * w);
    atomicAdd(o + 2, acc.z * w);
    atomicAdd(o + 3, acc.w * w);
}

extern "C" void kernel_launch(void* const* d_in, const int* in_sizes, int n_in,
                              void* d_out, int out_size, void* d_ws, size_t ws_size,
                              hipStream_t stream) {
    const float* feat   = (const float*)d_in[0];
    const float* W      = (const float*)d_in[1];
    const float* edge_w = (const float*)d_in[2];
    const int*   src    = (const int*)d_in[3];
    const int*   dst    = (const int*)d_in[4];
    float* out = (float*)d_out;

    int n = in_sizes[0] / N_IN;   // 100000
    int E = in_sizes[2];          // 1600000

    int NB  = (n + RANGE - 1) / RANGE;   // 1563
    int ncc = NCC;                       // 256
    int epc = (E + ncc - 1) / ncc;       // 6250

    size_t off_h   = 0;
    size_t off_tbl = (off_h + (size_t)n * N_OUT * sizeof(__half) + 15) & ~(size_t)15;
    size_t off_sw  = (off_tbl + (size_t)ncc * (NB + 1) * sizeof(int) + 15) & ~(size_t)15;
    size_t need    = off_sw + (size_t)ncc * epc * sizeof(int2);

    bool ok = (ws_size >= need) && (n <= (1 << 17)) && (NB <= MAXNB);

    if (ok) {
        char* ws = (char*)d_ws;
        __half* h  = (__half*)(ws + off_h);
        int*   tbl = (int*)(ws + off_tbl);
        int2*  sw  = (int2*)(ws + off_sw);

        long gthreads = (long)n * 8;
        gemm_h<<<(int)((gthreads + 255) / 256), 256, 0, stream>>>(feat, W, h, n);
        partition2_k<<<ncc, PBLK, 0, stream>>>(src, dst, edge_w, tbl, sw, E, NB, epc);
        conv3_k<<<NB, 256, 0, stream>>>(h, sw, tbl, out, n, NB, ncc, epc);
    } else {
        hipError_t _e = hipMemsetAsync(d_out, 0, (size_t)out_size * sizeof(float), stream);
        (void)_e;
        long sthreads = (long)E * 8;
        fused_edge<<<(int)((sthreads + 255) / 256), 256, 0, stream>>>(feat, W, edge_w, src, dst, out, E);
    }
}

// Round 12
// 78.652 us; speedup vs baseline: 1.3671x; 1.0213x over previous
//
#include <hip/hip_runtime.h>
#include <hip/hip_fp16.h>

constexpr int N_IN    = 128;
constexpr int N_OUT   = 32;
constexpr int LOG_R   = 6;
constexpr int RANGE   = 1 << LOG_R;  // 64 nodes per bucket
constexpr int MAXNB   = 2048;        // max buckets (LDS hist)
constexpr int NCC     = 256;         // edge chunks
constexpr int PBLK    = 512;         // partition2 threads
constexpr int CHUNK_P = 2048;        // staged pairs per conv pass

union H4 { uint2 u; __half2 h2[2]; };

// ---------------- Kernel 1: h = feat @ W  (h stored as f16) ----------------
__global__ __launch_bounds__(256) void gemm_h(
    const float* __restrict__ feat, const float* __restrict__ W,
    __half* __restrict__ h, int n)
{
    __shared__ float Ws[N_IN * N_OUT];  // 16 KB
    for (int i = threadIdx.x; i < (N_IN * N_OUT) / 4; i += 256)
        reinterpret_cast<float4*>(Ws)[i] = reinterpret_cast<const float4*>(W)[i];
    __syncthreads();

    int gid = blockIdx.x * 256 + threadIdx.x;
    int row = gid >> 3;
    if (row >= n) return;
    int cg = (gid & 7) * 4;

    const float4* frow = reinterpret_cast<const float4*>(feat + (size_t)row * N_IN);
    float4 acc = make_float4(0.f, 0.f, 0.f, 0.f);
    #pragma unroll
    for (int k4 = 0; k4 < N_IN / 4; ++k4) {
        float4 f = frow[k4];
        int k = k4 * 4;
        float4 w0 = *reinterpret_cast<const float4*>(&Ws[(k + 0) * N_OUT + cg]);
        float4 w1 = *reinterpret_cast<const float4*>(&Ws[(k + 1) * N_OUT + cg]);
        float4 w2 = *reinterpret_cast<const float4*>(&Ws[(k + 2) * N_OUT + cg]);
        float4 w3 = *reinterpret_cast<const float4*>(&Ws[(k + 3) * N_OUT + cg]);
        acc.x += f.x * w0.x + f.y * w1.x + f.z * w2.x + f.w * w3.x;
        acc.y += f.x * w0.y + f.y * w1.y + f.z * w2.y + f.w * w3.y;
        acc.z += f.x * w0.z + f.y * w1.z + f.z * w2.z + f.w * w3.z;
        acc.w += f.x * w0.w + f.y * w1.w + f.z * w2.w + f.w * w3.w;
    }
    H4 v;
    v.h2[0] = __float22half2_rn(make_float2(acc.x, acc.y));
    v.h2[1] = __float22half2_rn(make_float2(acc.z, acc.w));
    *reinterpret_cast<uint2*>(h + (size_t)row * N_OUT + cg) = v.u;
}

// ---------------- partition2: chunk-local sort, vectorized loads -----------
// epc is a multiple of 4 so e0*4B is 16B-aligned -> int4/float4 loads legal.
__global__ __launch_bounds__(PBLK) void partition2_k(
    const int* __restrict__ src, const int* __restrict__ dst,
    const float* __restrict__ w, int* __restrict__ tbl,
    int2* __restrict__ sw, int E, int NB, int epc)
{
    __shared__ int hist[MAXNB];
    __shared__ int wscan[PBLK];

    const int c   = blockIdx.x;
    const int tid = threadIdx.x;
    const int e0  = c * epc;
    const int e1  = min(e0 + epc, E);
    const int m   = max(e1 - e0, 0);
    const int m4  = m & ~3;
    const int slots = (NB + PBLK - 1) / PBLK;

    for (int i = tid; i < NB; i += PBLK) hist[i] = 0;
    __syncthreads();

    // pass 1: histogram (int4 loads, 4 independent atomics per iter)
    for (int o = tid * 4; o < m4; o += PBLK * 4) {
        int4 dv = *reinterpret_cast<const int4*>(dst + e0 + o);
        atomicAdd(&hist[dv.x >> LOG_R], 1);
        atomicAdd(&hist[dv.y >> LOG_R], 1);
        atomicAdd(&hist[dv.z >> LOG_R], 1);
        atomicAdd(&hist[dv.w >> LOG_R], 1);
    }
    if (m4 + tid < m) atomicAdd(&hist[dst[e0 + m4 + tid] >> LOG_R], 1);
    __syncthreads();

    // exclusive scan over NB counters
    int tsum = 0;
    int base = tid * slots;
    for (int j = 0; j < slots; ++j) {
        int idx = base + j;
        if (idx < NB) tsum += hist[idx];
    }
    wscan[tid] = tsum;
    __syncthreads();
    for (int off = 1; off < PBLK; off <<= 1) {
        int x = (tid >= off) ? wscan[tid - off] : 0;
        __syncthreads();
        wscan[tid] += x;
        __syncthreads();
    }
    int run = wscan[tid] - tsum;
    __syncthreads();
    for (int j = 0; j < slots; ++j) {
        int idx = base + j;
        if (idx < NB) {
            int cval = hist[idx];
            tbl[(size_t)c * (NB + 1) + idx] = run;
            hist[idx] = run;                        // becomes cursor
            run += cval;
        }
    }
    if (tid == 0) tbl[(size_t)c * (NB + 1) + NB] = m;
    __syncthreads();

    // pass 2: scatter pairs (vectorized reads)
    int2* outp = sw + (size_t)c * epc;
    for (int o = tid * 4; o < m4; o += PBLK * 4) {
        int4   sv = *reinterpret_cast<const int4*>(src + e0 + o);
        int4   dv = *reinterpret_cast<const int4*>(dst + e0 + o);
        float4 wv = *reinterpret_cast<const float4*>(w + e0 + o);
        int p0 = atomicAdd(&hist[dv.x >> LOG_R], 1);
        int p1 = atomicAdd(&hist[dv.y >> LOG_R], 1);
        int p2 = atomicAdd(&hist[dv.z >> LOG_R], 1);
        int p3 = atomicAdd(&hist[dv.w >> LOG_R], 1);
        outp[p0] = make_int2(sv.x | ((dv.x & (RANGE - 1)) << 17), __float_as_int(wv.x));
        outp[p1] = make_int2(sv.y | ((dv.y & (RANGE - 1)) << 17), __float_as_int(wv.y));
        outp[p2] = make_int2(sv.z | ((dv.z & (RANGE - 1)) << 17), __float_as_int(wv.z));
        outp[p3] = make_int2(sv.w | ((dv.w & (RANGE - 1)) << 17), __float_as_int(wv.w));
    }
    if (m4 + tid < m) {
        int e = e0 + m4 + tid;
        int d = dst[e];
        int pos = atomicAdd(&hist[d >> LOG_R], 1);
        outp[pos] = make_int2(src[e] | ((d & (RANGE - 1)) << 17), __float_as_int(w[e]));
    }
}

// ---------------- conv4: direct run-copy stage + sorted-scatter + reg acc --
__global__ __launch_bounds__(256) void conv4_k(
    const __half* __restrict__ h, const int2* __restrict__ sw,
    const int* __restrict__ tbl, float* __restrict__ out,
    int n, int NB, int ncc, int epc)
{
    __shared__ int2 pairs[CHUNK_P];     // 16 KB staging
    __shared__ int2 pairs_s[CHUNK_P];   // 16 KB node-sorted
    __shared__ int cnt[RANGE];
    __shared__ int sc[RANGE];
    __shared__ int start[RANGE + 1];
    __shared__ int cur[RANGE];
    __shared__ int rs[NCC];
    __shared__ int ps[NCC + 1];
    __shared__ int stmp[256];

    const int b   = blockIdx.x;
    const int tid = threadIdx.x;
    const int g   = tid >> 3;          // 0..31
    const int cg  = (tid & 7) * 4;

    // per-chunk run starts/lengths; prefix over chunks
    int len = 0;
    if (tid < ncc) {
        int s0 = tbl[(size_t)tid * (NB + 1) + b];
        int s1 = tbl[(size_t)tid * (NB + 1) + b + 1];
        rs[tid] = s0;
        len = s1 - s0;
    }
    stmp[tid] = len;
    __syncthreads();
    for (int off = 1; off < 256; off <<= 1) {
        int x = (tid >= off) ? stmp[tid - off] : 0;
        __syncthreads();
        stmp[tid] += x;
        __syncthreads();
    }
    ps[tid + 1] = stmp[tid];
    if (tid == 0) ps[0] = 0;
    __syncthreads();
    const int deg = ps[ncc];

    float4 accA = make_float4(0.f, 0.f, 0.f, 0.f);  // node 2g
    float4 accB = make_float4(0.f, 0.f, 0.f, 0.f);  // node 2g+1

    #define LOAD_H(p, f01, f23)                                                \
        H4 _u##f01;                                                            \
        _u##f01.u = *reinterpret_cast<const uint2*>(                           \
            h + (size_t)((p).x & 0x1FFFF) * N_OUT + cg);                       \
        float2 f01 = __half22float2(_u##f01.h2[0]);                            \
        float2 f23 = __half22float2(_u##f01.h2[1]);
    #define ACC_STEP(p, f01, f23)                                              \
    {                                                                          \
        float wv  = __int_as_float((p).y);                                     \
        int   odd = ((p).x >> 17) & 1;                                         \
        float wa = odd ? 0.f : wv, wb = odd ? wv : 0.f;                        \
        accA.x += f01.x * wa; accA.y += f01.y * wa;                            \
        accA.z += f23.x * wa; accA.w += f23.y * wa;                            \
        accB.x += f01.x * wb; accB.y += f01.y * wb;                            \
        accB.z += f23.x * wb; accB.w += f23.y * wb;                            \
    }

    if (deg <= CHUNK_P) {
        // ---- fast path: one pass, direct per-thread run copy (no search) ----
        if (tid < RANGE) cnt[tid] = 0;
        __syncthreads();

        if (tid < ncc) {
            int d0 = ps[tid];
            int l  = ps[tid + 1] - d0;
            const int2* sp = sw + (size_t)tid * epc + rs[tid];
            for (int j = 0; j < l; ++j) {
                int2 p = sp[j];
                pairs[d0 + j] = p;
                atomicAdd(&cnt[p.x >> 17], 1);
            }
        }
        __syncthreads();

        int v = 0;
        if (tid < RANGE) { v = cnt[tid]; sc[tid] = v; }
        __syncthreads();
        #pragma unroll
        for (int off = 1; off < RANGE; off <<= 1) {
            int x = (tid < RANGE && tid >= off) ? sc[tid - off] : 0;
            __syncthreads();
            if (tid < RANGE) sc[tid] += x;
            __syncthreads();
        }
        if (tid < RANGE) { start[tid] = sc[tid] - v; cur[tid] = sc[tid] - v; }
        if (tid == RANGE - 1) start[RANGE] = sc[RANGE - 1];
        __syncthreads();

        for (int i = tid; i < deg; i += 256) {
            int2 p = pairs[i];
            int pos = atomicAdd(&cur[p.x >> 17], 1);
            pairs_s[pos] = p;
        }
        __syncthreads();

        int k  = start[2 * g];
        int ke = start[2 * g + 2];
        for (; k + 3 < ke; k += 4) {
            int2 p0 = pairs_s[k + 0], p1 = pairs_s[k + 1];
            int2 p2 = pairs_s[k + 2], p3 = pairs_s[k + 3];
            LOAD_H(p0, a01, a23)
            LOAD_H(p1, b01, b23)
            LOAD_H(p2, c01, c23)
            LOAD_H(p3, d01, d23)
            ACC_STEP(p0, a01, a23)
            ACC_STEP(p1, b01, b23)
            ACC_STEP(p2, c01, c23)
            ACC_STEP(p3, d01, d23)
        }
        for (; k < ke; ++k) {
            int2 p = pairs_s[k];
            LOAD_H(p, e01, e23)
            ACC_STEP(p, e01, e23)
        }
    } else {
        // ---- fallback: windowed binary-search staging (rare) ----
        for (int cbase = 0; cbase < deg; cbase += CHUNK_P) {
            const int m = min(CHUNK_P, deg - cbase);

            for (int i = tid; i < m; i += 256) {
                int gidx = cbase + i;
                int lo = 0, hi = ncc - 1;
                while (lo < hi) {
                    int mid = (lo + hi + 1) >> 1;
                    if (ps[mid] <= gidx) lo = mid; else hi = mid - 1;
                }
                int off = gidx - ps[lo];
                pairs[i] = sw[(size_t)lo * epc + rs[lo] + off];
            }
            if (tid < RANGE) cnt[tid] = 0;
            __syncthreads();

            for (int i = tid; i < m; i += 256)
                atomicAdd(&cnt[pairs[i].x >> 17], 1);
            __syncthreads();

            int v = 0;
            if (tid < RANGE) { v = cnt[tid]; sc[tid] = v; }
            __syncthreads();
            #pragma unroll
            for (int off = 1; off < RANGE; off <<= 1) {
                int x = (tid < RANGE && tid >= off) ? sc[tid - off] : 0;
                __syncthreads();
                if (tid < RANGE) sc[tid] += x;
                __syncthreads();
            }
            if (tid < RANGE) { start[tid] = sc[tid] - v; cur[tid] = sc[tid] - v; }
            if (tid == RANGE - 1) start[RANGE] = sc[RANGE - 1];
            __syncthreads();

            for (int i = tid; i < m; i += 256) {
                int2 p = pairs[i];
                int pos = atomicAdd(&cur[p.x >> 17], 1);
                pairs_s[pos] = p;
            }
            __syncthreads();

            int k  = start[2 * g];
            int ke = start[2 * g + 2];
            for (; k < ke; ++k) {
                int2 p = pairs_s[k];
                LOAD_H(p, f01, f23)
                ACC_STEP(p, f01, f23)
            }
            __syncthreads();
        }
    }
    #undef LOAD_H
    #undef ACC_STEP

    const int lo2 = b * RANGE;
    int node0 = lo2 + 2 * g;
    if (node0 < n)
        *reinterpret_cast<float4*>(out + (size_t)node0 * N_OUT + cg) = accA;
    if (node0 + 1 < n)
        *reinterpret_cast<float4*>(out + (size_t)(node0 + 1) * N_OUT + cg) = accB;
}

// ---------------- Fallback: fused (no workspace) ----------------
__global__ __launch_bounds__(256) void fused_edge(
    const float* __restrict__ feat, const float* __restrict__ W,
    const float* __restrict__ edge_w, const int* __restrict__ src,
    const int* __restrict__ dst, float* __restrict__ out, int E)
{
    __shared__ float Ws[N_IN * N_OUT];
    for (int i = threadIdx.x; i < (N_IN * N_OUT) / 4; i += 256)
        reinterpret_cast<float4*>(Ws)[i] = reinterpret_cast<const float4*>(W)[i];
    __syncthreads();
    int gid = blockIdx.x * 256 + threadIdx.x;
    int e = gid >> 3;
    if (e >= E) return;
    int cg = (gid & 7) * 4;
    int s = src[e];
    int d = dst[e];
    float w = edge_w[e];
    const float4* frow = reinterpret_cast<const float4*>(feat + (size_t)s * N_IN);
    float4 acc = make_float4(0.f, 0.f, 0.f, 0.f);
    #pragma unroll
    for (int k4 = 0; k4 < N_IN / 4; ++k4) {
        float4 f = frow[k4];
        int k = k4 * 4;
        float4 w0 = *reinterpret_cast<const float4*>(&Ws[(k + 0) * N_OUT + cg]);
        float4 w1 = *reinterpret_cast<const float4*>(&Ws[(k + 1) * N_OUT + cg]);
        float4 w2 = *reinterpret_cast<const float4*>(&Ws[(k + 2) * N_OUT + cg]);
        float4 w3 = *reinterpret_cast<const float4*>(&Ws[(k + 3) * N_OUT + cg]);
        acc.x += f.x * w0.x + f.y * w1.x + f.z * w2.x + f.w * w3.x;
        acc.y += f.x * w0.y + f.y * w1.y + f.z * w2.y + f.w * w3.y;
        acc.z += f.x * w0.z + f.y * w1.z + f.z * w2.z + f.w * w3.z;
        acc.w += f.x * w0.w + f.y * w1.w + f.z * w2.w + f.w * w3.w;
    }
    float* o = out + (size_t)d * N_OUT + cg;
    atomicAdd(o + 0, acc.x * w);
    atomicAdd(o + 1, acc.y * w);
    atomicAdd(o + 2, acc.z * w);
    atomicAdd(o + 3, acc.w * w);
}

extern "C" void kernel_launch(void* const* d_in, const int* in_sizes, int n_in,
                              void* d_out, int out_size, void* d_ws, size_t ws_size,
                              hipStream_t stream) {
    const float* feat   = (const float*)d_in[0];
    const float* W      = (const float*)d_in[1];
    const float* edge_w = (const float*)d_in[2];
    const int*   src    = (const int*)d_in[3];
    const int*   dst    = (const int*)d_in[4];
    float* out = (float*)d_out;

    int n = in_sizes[0] / N_IN;   // 100000
    int E = in_sizes[2];          // 1600000

    int NB  = (n + RANGE - 1) / RANGE;             // 1563
    int ncc = NCC;                                 // 256
    int epc = (((E + ncc - 1) / ncc) + 3) & ~3;    // 6252 (x4 for 16B alignment)

    size_t off_h   = 0;
    size_t off_tbl = (off_h + (size_t)n * N_OUT * sizeof(__half) + 15) & ~(size_t)15;
    size_t off_sw  = (off_tbl + (size_t)ncc * (NB + 1) * sizeof(int) + 15) & ~(size_t)15;
    size_t need    = off_sw + (size_t)ncc * epc * sizeof(int2);

    bool ok = (ws_size >= need) && (n <= (1 << 17)) && (NB <= MAXNB);

    if (ok) {
        char* ws = (char*)d_ws;
        __half* h  = (__half*)(ws + off_h);
        int*   tbl = (int*)(ws + off_tbl);
        int2*  sw  = (int2*)(ws + off_sw);

        long gthreads = (long)n * 8;
        gemm_h<<<(int)((gthreads + 255) / 256), 256, 0, stream>>>(feat, W, h, n);
        partition2_k<<<ncc, PBLK, 0, stream>>>(src, dst, edge_w, tbl, sw, E, NB, epc);
        conv4_k<<<NB, 256, 0, stream>>>(h, sw, tbl, out, n, NB, ncc, epc);
    } else {
        hipError_t _e = hipMemsetAsync(d_out, 0, (size_t)out_size * sizeof(float), stream);
        (void)_e;
        long sthreads = (long)E * 8;
        fused_edge<<<(int)((sthreads + 255) / 256), 256, 0, stream>>>(feat, W, edge_w, src, dst, out, E);
    }
}